// Round 1
// baseline (5750.840 us; speedup 1.0000x reference)
//
#include <hip/hip_runtime.h>

#define N_NODES 100000
#define N_EDGES 3200000
#define F 128

// ---------------------------------------------------------------------------
// K0: out[i, :] = b[:]   (harness poisons d_out with 0xAA before every call)
// ---------------------------------------------------------------------------
__global__ void init_out_kernel(float* __restrict__ out, const float* __restrict__ b) {
    int idx = blockIdx.x * blockDim.x + threadIdx.x;   // float4 index
    const int total4 = N_NODES * F / 4;
    if (idx < total4) {
        int o4 = idx & (F / 4 - 1);                    // float4 position within row
        ((float4*)out)[idx] = ((const float4*)b)[o4];
    }
}

// ---------------------------------------------------------------------------
// K1: y = x @ W^T   ([N,128] = [N,128] @ [128,128]^T), y in d_ws
// One thread per node. x row -> 128 VGPRs; W rows are wave-uniform ->
// compiler emits s_load + scalar-operand v_fma. 16K FMA/thread.
// ---------------------------------------------------------------------------
__global__ void __launch_bounds__(256)
gemm_xwt_kernel(const float* __restrict__ x, const float* __restrict__ W,
                float* __restrict__ y) {
    int i = blockIdx.x * blockDim.x + threadIdx.x;
    if (i >= N_NODES) return;

    const float4* xrow = (const float4*)(x + (size_t)i * F);
    float4 xr[32];
#pragma unroll
    for (int k = 0; k < 32; ++k) xr[k] = xrow[k];

    float4* yrow = (float4*)(y + (size_t)i * F);

#pragma unroll 1
    for (int og = 0; og < 32; ++og) {                  // 4 output features per og
        const float4* w0 = (const float4*)(W + (size_t)(og * 4 + 0) * F);
        const float4* w1 = (const float4*)(W + (size_t)(og * 4 + 1) * F);
        const float4* w2 = (const float4*)(W + (size_t)(og * 4 + 2) * F);
        const float4* w3 = (const float4*)(W + (size_t)(og * 4 + 3) * F);
        float a0 = 0.f, a1 = 0.f, a2 = 0.f, a3 = 0.f;
#pragma unroll
        for (int k = 0; k < 32; ++k) {
            float4 xk = xr[k];
            float4 b0 = w0[k], b1 = w1[k], b2 = w2[k], b3 = w3[k];
            a0 += xk.x * b0.x + xk.y * b0.y + xk.z * b0.z + xk.w * b0.w;
            a1 += xk.x * b1.x + xk.y * b1.y + xk.z * b1.z + xk.w * b1.w;
            a2 += xk.x * b2.x + xk.y * b2.y + xk.z * b2.z + xk.w * b2.w;
            a3 += xk.x * b3.x + xk.y * b3.y + xk.z * b3.z + xk.w * b3.w;
        }
        float4 r; r.x = a0; r.y = a1; r.z = a2; r.w = a3;
        yrow[og] = r;
    }
}

// ---------------------------------------------------------------------------
// K2: out[rows[e], :] += vals[e] * y[cols[e], :]
// 32 lanes per edge, float4 per lane (512 B coalesced gather per edge).
// fp32 global atomics (global_atomic_add_f32, device scope, relaxed).
// ---------------------------------------------------------------------------
__global__ void __launch_bounds__(256)
scatter_edges_kernel(const int* __restrict__ rows, const int* __restrict__ cols,
                     const float* __restrict__ vals, const float* __restrict__ y,
                     float* __restrict__ out) {
    int t = blockIdx.x * blockDim.x + threadIdx.x;
    int e = t >> 5;
    int lane = t & 31;
    if (e >= N_EDGES) return;

    int r = rows[e];
    int c = cols[e];
    float v = vals[e];

    float4 m = ((const float4*)(y + (size_t)c * F))[lane];
    float* o = out + (size_t)r * F + lane * 4;

    __hip_atomic_fetch_add(o + 0, v * m.x, __ATOMIC_RELAXED, __HIP_MEMORY_SCOPE_AGENT);
    __hip_atomic_fetch_add(o + 1, v * m.y, __ATOMIC_RELAXED, __HIP_MEMORY_SCOPE_AGENT);
    __hip_atomic_fetch_add(o + 2, v * m.z, __ATOMIC_RELAXED, __HIP_MEMORY_SCOPE_AGENT);
    __hip_atomic_fetch_add(o + 3, v * m.w, __ATOMIC_RELAXED, __HIP_MEMORY_SCOPE_AGENT);
}

// ---------------------------------------------------------------------------
extern "C" void kernel_launch(void* const* d_in, const int* in_sizes, int n_in,
                              void* d_out, int out_size, void* d_ws, size_t ws_size,
                              hipStream_t stream) {
    const int*   L_rows = (const int*)d_in[0];
    const int*   L_cols = (const int*)d_in[1];
    const float* L_vals = (const float*)d_in[2];
    const float* x      = (const float*)d_in[3];
    const float* W      = (const float*)d_in[4];
    const float* b      = (const float*)d_in[5];
    float* out = (float*)d_out;
    float* y   = (float*)d_ws;                 // N_NODES*F*4 = 51.2 MB scratch

    // K0: out = b (broadcast)
    {
        int total4 = N_NODES * F / 4;
        int blocks = (total4 + 255) / 256;
        hipLaunchKernelGGL(init_out_kernel, dim3(blocks), dim3(256), 0, stream, out, b);
    }
    // K1: y = x @ W^T
    {
        int blocks = (N_NODES + 255) / 256;
        hipLaunchKernelGGL(gemm_xwt_kernel, dim3(blocks), dim3(256), 0, stream, x, W, y);
    }
    // K2: scatter-add edges into out
    {
        long long threads = (long long)N_EDGES * 32;
        int blocks = (int)((threads + 255) / 256);
        hipLaunchKernelGGL(scatter_edges_kernel, dim3(blocks), dim3(256), 0, stream,
                           L_rows, L_cols, L_vals, y, out);
    }
}

// Round 3
// 1181.678 us; speedup vs baseline: 4.8667x; 4.8667x over previous
//
#include <hip/hip_runtime.h>

#define N_NODES 100000
#define N_EDGES 3200000
#define F 128
#define SCAN_T 1024

// ---------------------------------------------------------------------------
// zero counts in-graph (hipMemsetAsync did not replay inside the captured
// graph -> counts accumulated across replays -> csr overrun. Kernel is safe.)
// ---------------------------------------------------------------------------
__global__ void zero_counts_kernel(int* __restrict__ counts) {
    int i = blockIdx.x * blockDim.x + threadIdx.x;
    if (i < N_NODES) counts[i] = 0;
}

// ---------------------------------------------------------------------------
// K1: y = x @ W^T   ([N,128] = [N,128] @ [128,128]^T), y in d_ws
// ---------------------------------------------------------------------------
__global__ void __launch_bounds__(256)
gemm_xwt_kernel(const float* __restrict__ x, const float* __restrict__ W,
                float* __restrict__ y) {
    int i = blockIdx.x * blockDim.x + threadIdx.x;
    if (i >= N_NODES) return;

    const float4* xrow = (const float4*)(x + (size_t)i * F);
    float4 xr[32];
#pragma unroll
    for (int k = 0; k < 32; ++k) xr[k] = xrow[k];

    float4* yrow = (float4*)(y + (size_t)i * F);

#pragma unroll 1
    for (int og = 0; og < 32; ++og) {
        const float4* w0 = (const float4*)(W + (size_t)(og * 4 + 0) * F);
        const float4* w1 = (const float4*)(W + (size_t)(og * 4 + 1) * F);
        const float4* w2 = (const float4*)(W + (size_t)(og * 4 + 2) * F);
        const float4* w3 = (const float4*)(W + (size_t)(og * 4 + 3) * F);
        float a0 = 0.f, a1 = 0.f, a2 = 0.f, a3 = 0.f;
#pragma unroll
        for (int k = 0; k < 32; ++k) {
            float4 xk = xr[k];
            float4 b0 = w0[k], b1 = w1[k], b2 = w2[k], b3 = w3[k];
            a0 += xk.x * b0.x + xk.y * b0.y + xk.z * b0.z + xk.w * b0.w;
            a1 += xk.x * b1.x + xk.y * b1.y + xk.z * b1.z + xk.w * b1.w;
            a2 += xk.x * b2.x + xk.y * b2.y + xk.z * b2.z + xk.w * b2.w;
            a3 += xk.x * b3.x + xk.y * b3.y + xk.z * b3.z + xk.w * b3.w;
        }
        float4 r; r.x = a0; r.y = a1; r.z = a2; r.w = a3;
        yrow[og] = r;
    }
}

// ---------------------------------------------------------------------------
// CSR build: histogram -> scan -> scatter
// ---------------------------------------------------------------------------
__global__ void hist_kernel(const int* __restrict__ rows, int* __restrict__ counts) {
    int e = blockIdx.x * blockDim.x + threadIdx.x;
    if (e < N_EDGES) atomicAdd(&counts[rows[e]], 1);
}

// Single-block exclusive scan over counts[N_NODES] -> row_ptr[N_NODES+1], cursor copy
__global__ void __launch_bounds__(SCAN_T)
scan_kernel(const int* __restrict__ counts, int* __restrict__ row_ptr,
            int* __restrict__ cursor) {
    __shared__ int partial[SCAN_T];
    int tid = threadIdx.x;
    const int chunk = (N_NODES + SCAN_T - 1) / SCAN_T;  // 98
    int begin = tid * chunk;
    int end   = min(begin + chunk, N_NODES);

    int s = 0;
    for (int i = begin; i < end; ++i) s += counts[i];
    partial[tid] = s;
    __syncthreads();

    for (int off = 1; off < SCAN_T; off <<= 1) {
        int v = (tid >= off) ? partial[tid - off] : 0;
        __syncthreads();
        partial[tid] += v;
        __syncthreads();
    }
    int run = (tid == 0) ? 0 : partial[tid - 1];

    for (int i = begin; i < end; ++i) {
        row_ptr[i] = run;
        cursor[i]  = run;
        run += counts[i];
    }
    if (tid == SCAN_T - 1) row_ptr[N_NODES] = run;  // == N_EDGES
}

__global__ void scatter_csr_kernel(const int* __restrict__ rows,
                                   const int* __restrict__ cols,
                                   const float* __restrict__ vals,
                                   int* __restrict__ cursor, int2* __restrict__ csr) {
    int e = blockIdx.x * blockDim.x + threadIdx.x;
    if (e < N_EDGES) {
        int r = rows[e];
        int pos = atomicAdd(&cursor[r], 1);
        int2 cv;
        cv.x = cols[e];
        cv.y = __float_as_int(vals[e]);
        csr[pos] = cv;
    }
}

// ---------------------------------------------------------------------------
// Aggregate: one wave (64 lanes) per node, no atomics.
// lane l owns float2 features [2l, 2l+1]; out[i,:] = b + sum val*y[col,:]
// ---------------------------------------------------------------------------
__global__ void __launch_bounds__(256)
aggregate_kernel(const int* __restrict__ row_ptr, const int2* __restrict__ csr,
                 const float* __restrict__ y, const float* __restrict__ b,
                 float* __restrict__ out) {
    int node = (blockIdx.x * blockDim.x + threadIdx.x) >> 6;
    int lane = threadIdx.x & 63;
    if (node >= N_NODES) return;

    int start = row_ptr[node];
    int end   = row_ptr[node + 1];

    float2 acc = ((const float2*)b)[lane];

    int e = start;
    for (; e + 4 <= end; e += 4) {
        int2 cv0 = csr[e + 0];
        int2 cv1 = csr[e + 1];
        int2 cv2 = csr[e + 2];
        int2 cv3 = csr[e + 3];
        float2 m0 = ((const float2*)(y + (size_t)cv0.x * F))[lane];
        float2 m1 = ((const float2*)(y + (size_t)cv1.x * F))[lane];
        float2 m2 = ((const float2*)(y + (size_t)cv2.x * F))[lane];
        float2 m3 = ((const float2*)(y + (size_t)cv3.x * F))[lane];
        float v0 = __int_as_float(cv0.y);
        float v1 = __int_as_float(cv1.y);
        float v2 = __int_as_float(cv2.y);
        float v3 = __int_as_float(cv3.y);
        acc.x += v0 * m0.x; acc.y += v0 * m0.y;
        acc.x += v1 * m1.x; acc.y += v1 * m1.y;
        acc.x += v2 * m2.x; acc.y += v2 * m2.y;
        acc.x += v3 * m3.x; acc.y += v3 * m3.y;
    }
    for (; e < end; ++e) {
        int2 cv = csr[e];
        float2 m = ((const float2*)(y + (size_t)cv.x * F))[lane];
        float v = __int_as_float(cv.y);
        acc.x += v * m.x; acc.y += v * m.y;
    }
    ((float2*)(out + (size_t)node * F))[lane] = acc;
}

// ---------------------------------------------------------------------------
// Fallback path (ws too small for CSR): bias-init + fp32 atomic scatter
// ---------------------------------------------------------------------------
__global__ void init_out_kernel(float* __restrict__ out, const float* __restrict__ b) {
    int idx = blockIdx.x * blockDim.x + threadIdx.x;
    const int total4 = N_NODES * F / 4;
    if (idx < total4) {
        int o4 = idx & (F / 4 - 1);
        ((float4*)out)[idx] = ((const float4*)b)[o4];
    }
}

__global__ void __launch_bounds__(256)
scatter_edges_kernel(const int* __restrict__ rows, const int* __restrict__ cols,
                     const float* __restrict__ vals, const float* __restrict__ y,
                     float* __restrict__ out) {
    int t = blockIdx.x * blockDim.x + threadIdx.x;
    int e = t >> 5;
    int lane = t & 31;
    if (e >= N_EDGES) return;
    int r = rows[e];
    int c = cols[e];
    float v = vals[e];
    float4 m = ((const float4*)(y + (size_t)c * F))[lane];
    float* o = out + (size_t)r * F + lane * 4;
    __hip_atomic_fetch_add(o + 0, v * m.x, __ATOMIC_RELAXED, __HIP_MEMORY_SCOPE_AGENT);
    __hip_atomic_fetch_add(o + 1, v * m.y, __ATOMIC_RELAXED, __HIP_MEMORY_SCOPE_AGENT);
    __hip_atomic_fetch_add(o + 2, v * m.z, __ATOMIC_RELAXED, __HIP_MEMORY_SCOPE_AGENT);
    __hip_atomic_fetch_add(o + 3, v * m.w, __ATOMIC_RELAXED, __HIP_MEMORY_SCOPE_AGENT);
}

// ---------------------------------------------------------------------------
extern "C" void kernel_launch(void* const* d_in, const int* in_sizes, int n_in,
                              void* d_out, int out_size, void* d_ws, size_t ws_size,
                              hipStream_t stream) {
    const int*   L_rows = (const int*)d_in[0];
    const int*   L_cols = (const int*)d_in[1];
    const float* L_vals = (const float*)d_in[2];
    const float* x      = (const float*)d_in[3];
    const float* W      = (const float*)d_in[4];
    const float* b      = (const float*)d_in[5];
    float* out = (float*)d_out;

    // Workspace layout (bytes, all 16B-aligned):
    //   y       @ 0          : N*F*4        = 51,200,000
    //   counts  @ 51,200,000 : N*4          =    400,000
    //   row_ptr @ 51,600,000 : (N+1)*4      -> padded 400,016
    //   cursor  @ 52,000,016 : N*4          =    400,000
    //   csr     @ 52,400,016 : E*8          = 25,600,000
    // total = 78,000,016
    const size_t OFF_Y      = 0;
    const size_t OFF_COUNTS = 51200000;
    const size_t OFF_ROWPTR = 51600000;
    const size_t OFF_CURSOR = 52000016;
    const size_t OFF_CSR    = 52400016;
    const size_t WS_NEEDED  = 78000016;

    char* ws = (char*)d_ws;
    float* y = (float*)(ws + OFF_Y);

    if (ws_size >= WS_NEEDED) {
        int*  counts  = (int*)(ws + OFF_COUNTS);
        int*  row_ptr = (int*)(ws + OFF_ROWPTR);
        int*  cursor  = (int*)(ws + OFF_CURSOR);
        int2* csr     = (int2*)(ws + OFF_CSR);

        hipLaunchKernelGGL(zero_counts_kernel, dim3((N_NODES + 255) / 256), dim3(256), 0,
                           stream, counts);
        hipLaunchKernelGGL(hist_kernel, dim3((N_EDGES + 255) / 256), dim3(256), 0, stream,
                           L_rows, counts);
        hipLaunchKernelGGL(scan_kernel, dim3(1), dim3(SCAN_T), 0, stream,
                           counts, row_ptr, cursor);
        hipLaunchKernelGGL(scatter_csr_kernel, dim3((N_EDGES + 255) / 256), dim3(256), 0,
                           stream, L_rows, L_cols, L_vals, cursor, csr);
        hipLaunchKernelGGL(gemm_xwt_kernel, dim3((N_NODES + 255) / 256), dim3(256), 0,
                           stream, x, W, y);
        // one wave per node -> 4 nodes per 256-thread block
        hipLaunchKernelGGL(aggregate_kernel, dim3((N_NODES + 3) / 4), dim3(256), 0,
                           stream, row_ptr, csr, y, b, out);
    } else {
        // Fallback: atomic scatter path
        int total4 = N_NODES * F / 4;
        hipLaunchKernelGGL(init_out_kernel, dim3((total4 + 255) / 256), dim3(256), 0,
                           stream, out, b);
        hipLaunchKernelGGL(gemm_xwt_kernel, dim3((N_NODES + 255) / 256), dim3(256), 0,
                           stream, x, W, y);
        long long threads = (long long)N_EDGES * 32;
        hipLaunchKernelGGL(scatter_edges_kernel, dim3((int)((threads + 255) / 256)),
                           dim3(256), 0, stream, L_rows, L_cols, L_vals, y, out);
    }
}

// Round 4
// 944.240 us; speedup vs baseline: 6.0904x; 1.2515x over previous
//
#include <hip/hip_runtime.h>

#define N_NODES 100000
#define N_EDGES 3200000
#define F 128
#define SCAN_T 1024

typedef __attribute__((ext_vector_type(8))) short bf16x8;
typedef __attribute__((ext_vector_type(4))) float f32x4;

// round-to-nearest-even fp32 -> bf16 bits
__device__ __forceinline__ unsigned rne_bf16(float v) {
    unsigned u = __float_as_uint(v);
    return (u + 0x7FFFu + ((u >> 16) & 1u)) >> 16;
}

// ---------------------------------------------------------------------------
// GEMM: y = x @ W^T via split-bf16 MFMA (3 passes: hi*hi + lo*hi + hi*lo).
// W staged once per block into LDS, pre-swizzled into B-fragment order:
// frag(ntile,chunk): lane -> 8 contiguous bf16 (16 B) => conflict-free b128.
// One wave = 16 nodes; 512-thr block = 8 waves = 128 nodes.
// ---------------------------------------------------------------------------
__global__ void __launch_bounds__(512, 4)
gemm_mfma_kernel(const float* __restrict__ x, const float* __restrict__ W,
                 float* __restrict__ y) {
    __shared__ unsigned short wlds[32768];   // hi[0,16384) lo[16384,32768) = 64 KB
    int tid = threadIdx.x;

    // ---- stage W: 4096 float4s over 512 threads = 8 each ----
#pragma unroll
    for (int it = 0; it < 8; ++it) {
        int idx4 = tid + it * 512;           // float4 index into W
        int n    = idx4 >> 5;                // output-feature row (W is [n][k])
        int k4   = idx4 & 31;
        float4 v = ((const float4*)W)[idx4];
        int k0    = k4 * 4;
        int chunk = k0 >> 5;                 // K-chunk of 32
        int quadw = (k0 >> 3) & 3;
        int j0    = k0 & 7;                  // 0 or 4
        int lanef = quadw * 16 + (n & 15);   // B-frag lane: n=lane&15, k=quad*8+j
        int ntile = n >> 4;
        int base  = ((ntile * 4 + chunk) * 64 + lanef) * 8 + j0;
        float vv[4] = {v.x, v.y, v.z, v.w};
#pragma unroll
        for (int e = 0; e < 4; ++e) {
            unsigned hi = rne_bf16(vv[e]);
            float hf    = __uint_as_float(hi << 16);
            unsigned lo = rne_bf16(vv[e] - hf);
            wlds[base + e]         = (unsigned short)hi;
            wlds[16384 + base + e] = (unsigned short)lo;
        }
    }
    __syncthreads();

    int wave = tid >> 6, lane = tid & 63;
    int quad = lane >> 4, l16 = lane & 15;
    int nodeBase = blockIdx.x * 128 + wave * 16;
    if (nodeBase >= N_NODES) return;         // 100000/16=6250 exact; whole-wave exit

    // ---- A fragments: x[nodeBase + (lane&15)][k = c*32 + quad*8 + j], split ----
    bf16x8 a_hi[4], a_lo[4];
    const float* xrow = x + (size_t)(nodeBase + l16) * F + quad * 8;
#pragma unroll
    for (int c = 0; c < 4; ++c) {
        float4 p0 = *(const float4*)(xrow + c * 32);
        float4 p1 = *(const float4*)(xrow + c * 32 + 4);
        float vv[8] = {p0.x, p0.y, p0.z, p0.w, p1.x, p1.y, p1.z, p1.w};
#pragma unroll
        for (int j = 0; j < 8; ++j) {
            unsigned hi = rne_bf16(vv[j]);
            float hf    = __uint_as_float(hi << 16);
            unsigned lo = rne_bf16(vv[j] - hf);
            a_hi[c][j] = (short)hi;
            a_lo[c][j] = (short)lo;
        }
    }

    // ---- 8 n-tiles x 4 k-chunks x 3 MFMA; C/D: row=quad*4+reg, col=lane&15 ----
#pragma unroll 1
    for (int nt = 0; nt < 8; ++nt) {
        f32x4 acc = {0.f, 0.f, 0.f, 0.f};
#pragma unroll
        for (int c = 0; c < 4; ++c) {
            int fo = ((nt * 4 + c) * 64 + lane) * 8;
            bf16x8 b_hi = *(const bf16x8*)&wlds[fo];
            bf16x8 b_lo = *(const bf16x8*)&wlds[16384 + fo];
            acc = __builtin_amdgcn_mfma_f32_16x16x32_bf16(a_hi[c], b_hi, acc, 0, 0, 0);
            acc = __builtin_amdgcn_mfma_f32_16x16x32_bf16(a_lo[c], b_hi, acc, 0, 0, 0);
            acc = __builtin_amdgcn_mfma_f32_16x16x32_bf16(a_hi[c], b_lo, acc, 0, 0, 0);
        }
        float* yo = y + (size_t)(nodeBase + quad * 4) * F + nt * 16 + l16;
        yo[0 * F] = acc[0];
        yo[1 * F] = acc[1];
        yo[2 * F] = acc[2];
        yo[3 * F] = acc[3];
    }
}

// ---------------------------------------------------------------------------
// zero counts in-graph (hipMemsetAsync does not replay inside captured graph)
// ---------------------------------------------------------------------------
__global__ void zero_counts_kernel(int* __restrict__ counts) {
    int i = blockIdx.x * blockDim.x + threadIdx.x;
    if (i < N_NODES) counts[i] = 0;
}

// ---------------------------------------------------------------------------
// CSR build: histogram -> scan -> scatter
// ---------------------------------------------------------------------------
__global__ void hist_kernel(const int* __restrict__ rows, int* __restrict__ counts) {
    int e = blockIdx.x * blockDim.x + threadIdx.x;
    if (e < N_EDGES) atomicAdd(&counts[rows[e]], 1);
}

__global__ void __launch_bounds__(SCAN_T)
scan_kernel(const int* __restrict__ counts, int* __restrict__ row_ptr,
            int* __restrict__ cursor) {
    __shared__ int partial[SCAN_T];
    int tid = threadIdx.x;
    const int chunk = (N_NODES + SCAN_T - 1) / SCAN_T;  // 98
    int begin = tid * chunk;
    int end   = min(begin + chunk, N_NODES);

    int s = 0;
    for (int i = begin; i < end; ++i) s += counts[i];
    partial[tid] = s;
    __syncthreads();

    for (int off = 1; off < SCAN_T; off <<= 1) {
        int v = (tid >= off) ? partial[tid - off] : 0;
        __syncthreads();
        partial[tid] += v;
        __syncthreads();
    }
    int run = (tid == 0) ? 0 : partial[tid - 1];

    for (int i = begin; i < end; ++i) {
        row_ptr[i] = run;
        cursor[i]  = run;
        run += counts[i];
    }
    if (tid == SCAN_T - 1) row_ptr[N_NODES] = run;  // == N_EDGES
}

__global__ void scatter_csr_kernel(const int* __restrict__ rows,
                                   const int* __restrict__ cols,
                                   const float* __restrict__ vals,
                                   int* __restrict__ cursor, int2* __restrict__ csr) {
    int e = blockIdx.x * blockDim.x + threadIdx.x;
    if (e < N_EDGES) {
        int r = rows[e];
        int pos = atomicAdd(&cursor[r], 1);
        int2 cv;
        cv.x = cols[e];
        cv.y = __float_as_int(vals[e]);
        csr[pos] = cv;
    }
}

// ---------------------------------------------------------------------------
// Aggregate: one wave per node, no atomics; fused bias.
// ---------------------------------------------------------------------------
__global__ void __launch_bounds__(256)
aggregate_kernel(const int* __restrict__ row_ptr, const int2* __restrict__ csr,
                 const float* __restrict__ y, const float* __restrict__ b,
                 float* __restrict__ out) {
    int node = (blockIdx.x * blockDim.x + threadIdx.x) >> 6;
    int lane = threadIdx.x & 63;
    if (node >= N_NODES) return;

    int start = row_ptr[node];
    int end   = row_ptr[node + 1];

    float2 acc = ((const float2*)b)[lane];

    int e = start;
    for (; e + 4 <= end; e += 4) {
        int2 cv0 = csr[e + 0];
        int2 cv1 = csr[e + 1];
        int2 cv2 = csr[e + 2];
        int2 cv3 = csr[e + 3];
        float2 m0 = ((const float2*)(y + (size_t)cv0.x * F))[lane];
        float2 m1 = ((const float2*)(y + (size_t)cv1.x * F))[lane];
        float2 m2 = ((const float2*)(y + (size_t)cv2.x * F))[lane];
        float2 m3 = ((const float2*)(y + (size_t)cv3.x * F))[lane];
        float v0 = __int_as_float(cv0.y);
        float v1 = __int_as_float(cv1.y);
        float v2 = __int_as_float(cv2.y);
        float v3 = __int_as_float(cv3.y);
        acc.x += v0 * m0.x; acc.y += v0 * m0.y;
        acc.x += v1 * m1.x; acc.y += v1 * m1.y;
        acc.x += v2 * m2.x; acc.y += v2 * m2.y;
        acc.x += v3 * m3.x; acc.y += v3 * m3.y;
    }
    for (; e < end; ++e) {
        int2 cv = csr[e];
        float2 m = ((const float2*)(y + (size_t)cv.x * F))[lane];
        float v = __int_as_float(cv.y);
        acc.x += v * m.x; acc.y += v * m.y;
    }
    ((float2*)(out + (size_t)node * F))[lane] = acc;
}

// ---------------------------------------------------------------------------
// Fallback path (ws too small for CSR): bias-init + fp32 atomic scatter
// ---------------------------------------------------------------------------
__global__ void init_out_kernel(float* __restrict__ out, const float* __restrict__ b) {
    int idx = blockIdx.x * blockDim.x + threadIdx.x;
    const int total4 = N_NODES * F / 4;
    if (idx < total4) {
        int o4 = idx & (F / 4 - 1);
        ((float4*)out)[idx] = ((const float4*)b)[o4];
    }
}

__global__ void __launch_bounds__(256)
scatter_edges_kernel(const int* __restrict__ rows, const int* __restrict__ cols,
                     const float* __restrict__ vals, const float* __restrict__ y,
                     float* __restrict__ out) {
    int t = blockIdx.x * blockDim.x + threadIdx.x;
    int e = t >> 5;
    int lane = t & 31;
    if (e >= N_EDGES) return;
    int r = rows[e];
    int c = cols[e];
    float v = vals[e];
    float4 m = ((const float4*)(y + (size_t)c * F))[lane];
    float* o = out + (size_t)r * F + lane * 4;
    __hip_atomic_fetch_add(o + 0, v * m.x, __ATOMIC_RELAXED, __HIP_MEMORY_SCOPE_AGENT);
    __hip_atomic_fetch_add(o + 1, v * m.y, __ATOMIC_RELAXED, __HIP_MEMORY_SCOPE_AGENT);
    __hip_atomic_fetch_add(o + 2, v * m.z, __ATOMIC_RELAXED, __HIP_MEMORY_SCOPE_AGENT);
    __hip_atomic_fetch_add(o + 3, v * m.w, __ATOMIC_RELAXED, __HIP_MEMORY_SCOPE_AGENT);
}

// ---------------------------------------------------------------------------
extern "C" void kernel_launch(void* const* d_in, const int* in_sizes, int n_in,
                              void* d_out, int out_size, void* d_ws, size_t ws_size,
                              hipStream_t stream) {
    const int*   L_rows = (const int*)d_in[0];
    const int*   L_cols = (const int*)d_in[1];
    const float* L_vals = (const float*)d_in[2];
    const float* x      = (const float*)d_in[3];
    const float* W      = (const float*)d_in[4];
    const float* b      = (const float*)d_in[5];
    float* out = (float*)d_out;

    // Workspace layout (bytes):
    //   y       @ 0          : N*F*4   = 51,200,000
    //   counts  @ 51,200,000 : N*4
    //   row_ptr @ 51,600,000 : (N+1)*4 (padded)
    //   cursor  @ 52,000,016 : N*4
    //   csr     @ 52,400,016 : E*8     = 25,600,000
    const size_t OFF_COUNTS = 51200000;
    const size_t OFF_ROWPTR = 51600000;
    const size_t OFF_CURSOR = 52000016;
    const size_t OFF_CSR    = 52400016;
    const size_t WS_NEEDED  = 78000016;

    char* ws = (char*)d_ws;
    float* y = (float*)ws;

    const int gemm_blocks = (N_NODES + 127) / 128;  // 782

    if (ws_size >= WS_NEEDED) {
        int*  counts  = (int*)(ws + OFF_COUNTS);
        int*  row_ptr = (int*)(ws + OFF_ROWPTR);
        int*  cursor  = (int*)(ws + OFF_CURSOR);
        int2* csr     = (int2*)(ws + OFF_CSR);

        hipLaunchKernelGGL(zero_counts_kernel, dim3((N_NODES + 255) / 256), dim3(256), 0,
                           stream, counts);
        hipLaunchKernelGGL(hist_kernel, dim3((N_EDGES + 255) / 256), dim3(256), 0, stream,
                           L_rows, counts);
        hipLaunchKernelGGL(scan_kernel, dim3(1), dim3(SCAN_T), 0, stream,
                           counts, row_ptr, cursor);
        hipLaunchKernelGGL(scatter_csr_kernel, dim3((N_EDGES + 255) / 256), dim3(256), 0,
                           stream, L_rows, L_cols, L_vals, cursor, csr);
        hipLaunchKernelGGL(gemm_mfma_kernel, dim3(gemm_blocks), dim3(512), 0, stream,
                           x, W, y);
        hipLaunchKernelGGL(aggregate_kernel, dim3((N_NODES + 3) / 4), dim3(256), 0,
                           stream, row_ptr, csr, y, b, out);
    } else {
        int total4 = N_NODES * F / 4;
        hipLaunchKernelGGL(init_out_kernel, dim3((total4 + 255) / 256), dim3(256), 0,
                           stream, out, b);
        hipLaunchKernelGGL(gemm_mfma_kernel, dim3(gemm_blocks), dim3(512), 0, stream,
                           x, W, y);
        long long threads = (long long)N_EDGES * 32;
        hipLaunchKernelGGL(scatter_edges_kernel, dim3((int)((threads + 255) / 256)),
                           dim3(256), 0, stream, L_rows, L_cols, L_vals, y, out);
    }
}

// Round 5
// 539.101 us; speedup vs baseline: 10.6675x; 1.7515x over previous
//
#include <hip/hip_runtime.h>

#define N_NODES 100000
#define N_EDGES 3200000
#define F 128
#define GEMM_BLOCKS 782   // ceil(100000 / 128)
#define SCAT_BLOCKS 6250  // 3.2M / 512
#define NB_SCAN 391       // ceil(100000 / 256)

typedef __attribute__((ext_vector_type(8))) short bf16x8;
typedef __attribute__((ext_vector_type(4))) float f32x4;

// round-to-nearest-even fp32 -> bf16 bits
__device__ __forceinline__ unsigned rne_bf16(float v) {
    unsigned u = __float_as_uint(v);
    return (u + 0x7FFFu + ((u >> 16) & 1u)) >> 16;
}

// ---------------------------------------------------------------------------
// K1: zero padded counts (counts_p[r*16]; 1.6M ints = 6.4 MB, full-line writes)
// ---------------------------------------------------------------------------
__global__ void zero_counts_kernel(int4* __restrict__ p) {
    int i = blockIdx.x * blockDim.x + threadIdx.x;
    if (i < 400000) p[i] = make_int4(0, 0, 0, 0);
}

// ---------------------------------------------------------------------------
// K2: histogram. counts padded to 1 row per 64B line -> 32 RMW/line not 512.
// ---------------------------------------------------------------------------
__global__ void hist_kernel(const int* __restrict__ rows, int* __restrict__ counts_p) {
    int e = blockIdx.x * blockDim.x + threadIdx.x;
    if (e < N_EDGES) atomicAdd(&counts_p[rows[e] << 4], 1);
}

// ---------------------------------------------------------------------------
// K3/K4/K5: 3-level exclusive scan over padded counts -> row_ptr + cursor_p
// ---------------------------------------------------------------------------
__global__ void __launch_bounds__(256)
scanA_kernel(const int* __restrict__ counts_p, int* __restrict__ block_sums) {
    __shared__ int red[256];
    int tid = threadIdx.x;
    int r = blockIdx.x * 256 + tid;
    red[tid] = (r < N_NODES) ? counts_p[r << 4] : 0;
    __syncthreads();
    for (int off = 128; off > 0; off >>= 1) {
        if (tid < off) red[tid] += red[tid + off];
        __syncthreads();
    }
    if (tid == 0) block_sums[blockIdx.x] = red[0];
}

__global__ void __launch_bounds__(512)
scanB_kernel(const int* __restrict__ block_sums, int* __restrict__ bases,
             int* __restrict__ row_ptr) {
    __shared__ int s[512];
    int tid = threadIdx.x;
    s[tid] = (tid < NB_SCAN) ? block_sums[tid] : 0;
    __syncthreads();
    for (int off = 1; off < 512; off <<= 1) {
        int v = (tid >= off) ? s[tid - off] : 0;
        __syncthreads();
        s[tid] += v;
        __syncthreads();
    }
    if (tid < NB_SCAN) bases[tid] = (tid == 0) ? 0 : s[tid - 1];
    if (tid == 0) row_ptr[N_NODES] = N_EDGES;
}

__global__ void __launch_bounds__(256)
scanC_kernel(const int* __restrict__ counts_p, const int* __restrict__ bases,
             int* __restrict__ row_ptr, int* __restrict__ cursor_p) {
    __shared__ int s[256];
    int tid = threadIdx.x;
    int r = blockIdx.x * 256 + tid;
    s[tid] = (r < N_NODES) ? counts_p[r << 4] : 0;
    __syncthreads();
    for (int off = 1; off < 256; off <<= 1) {
        int v = (tid >= off) ? s[tid - off] : 0;
        __syncthreads();
        s[tid] += v;
        __syncthreads();
    }
    int excl = ((tid == 0) ? 0 : s[tid - 1]) + bases[blockIdx.x];
    if (r < N_NODES) {
        row_ptr[r] = excl;
        cursor_p[r << 4] = excl;
    }
}

// ---------------------------------------------------------------------------
// K6 (fat): blocks [0,GEMM_BLOCKS) -> y16 = bf16(x @ W^T); rest -> csr scatter.
// GEMM: hi-only bf16 MFMA (y is bf16 anyway, split precision is moot).
// W staged in LDS pre-swizzled to B-fragment order (32 KB).
// ---------------------------------------------------------------------------
__global__ void __launch_bounds__(512, 4)
fat_gemm_scatter_kernel(const float* __restrict__ x, const float* __restrict__ W,
                        unsigned short* __restrict__ y16,
                        const int* __restrict__ rows, const int* __restrict__ cols,
                        const float* __restrict__ vals,
                        int* __restrict__ cursor_p, int2* __restrict__ csr) {
    __shared__ unsigned short wlds[16384];   // W-hi in B-frag order, 32 KB
    int tid = threadIdx.x;

    if (blockIdx.x >= GEMM_BLOCKS) {
        // ---- scatter path: build csr sorted by row ----
        int e = (blockIdx.x - GEMM_BLOCKS) * 512 + tid;
        if (e < N_EDGES) {
            int r = rows[e];
            int c = cols[e];
            float v = vals[e];
            int pos = atomicAdd(&cursor_p[r << 4], 1);
            int2 cv;
            cv.x = c;
            cv.y = __float_as_int(v);
            csr[pos] = cv;
        }
        return;
    }

    // ---- gemm path ----
    // stage W: 4096 float4s over 512 threads = 8 each, swizzled to frag order
#pragma unroll
    for (int it = 0; it < 8; ++it) {
        int idx4 = tid + it * 512;
        int n    = idx4 >> 5;                // W row (output feature)
        int k4   = idx4 & 31;
        float4 v = ((const float4*)W)[idx4];
        int k0    = k4 * 4;
        int chunk = k0 >> 5;
        int quadw = (k0 >> 3) & 3;
        int j0    = k0 & 7;
        int lanef = quadw * 16 + (n & 15);
        int ntile = n >> 4;
        int base  = ((ntile * 4 + chunk) * 64 + lanef) * 8 + j0;
        float vv[4] = {v.x, v.y, v.z, v.w};
#pragma unroll
        for (int e = 0; e < 4; ++e)
            wlds[base + e] = (unsigned short)rne_bf16(vv[e]);
    }
    __syncthreads();

    int wave = tid >> 6, lane = tid & 63;
    int quad = lane >> 4, l16 = lane & 15;
    int nodeBase = blockIdx.x * 128 + wave * 16;
    if (nodeBase >= N_NODES) return;

    // A fragments: x[nodeBase + l16][k = c*32 + quad*8 + j]
    bf16x8 a_hi[4];
    const float* xrow = x + (size_t)(nodeBase + l16) * F + quad * 8;
#pragma unroll
    for (int c = 0; c < 4; ++c) {
        float4 p0 = *(const float4*)(xrow + c * 32);
        float4 p1 = *(const float4*)(xrow + c * 32 + 4);
        float vv[8] = {p0.x, p0.y, p0.z, p0.w, p1.x, p1.y, p1.z, p1.w};
#pragma unroll
        for (int j = 0; j < 8; ++j) a_hi[c][j] = (short)rne_bf16(vv[j]);
    }

#pragma unroll 1
    for (int nt = 0; nt < 8; ++nt) {
        f32x4 acc = {0.f, 0.f, 0.f, 0.f};
#pragma unroll
        for (int c = 0; c < 4; ++c) {
            int fo = ((nt * 4 + c) * 64 + lane) * 8;
            bf16x8 b_hi = *(const bf16x8*)&wlds[fo];
            acc = __builtin_amdgcn_mfma_f32_16x16x32_bf16(a_hi[c], b_hi, acc, 0, 0, 0);
        }
        // C/D: row = quad*4 + r (node), col = nt*16 + l16 (out feature)
#pragma unroll
        for (int r = 0; r < 4; ++r)
            y16[(size_t)(nodeBase + quad * 4 + r) * F + nt * 16 + l16] =
                (unsigned short)rne_bf16(acc[r]);
    }
}

// ---------------------------------------------------------------------------
// K7: aggregate, one wave per node, no atomics; bf16 y gather (256 B/edge).
// ---------------------------------------------------------------------------
__global__ void __launch_bounds__(256)
aggregate_kernel(const int* __restrict__ row_ptr, const int2* __restrict__ csr,
                 const unsigned* __restrict__ y16u, const float* __restrict__ b,
                 float* __restrict__ out) {
    int node = (blockIdx.x * blockDim.x + threadIdx.x) >> 6;
    int lane = threadIdx.x & 63;
    if (node >= N_NODES) return;

    int start = row_ptr[node];
    int end   = row_ptr[node + 1];

    float2 acc = ((const float2*)b)[lane];   // features 2*lane, 2*lane+1

    int e = start;
    for (; e + 4 <= end; e += 4) {
        int2 cv0 = csr[e + 0];
        int2 cv1 = csr[e + 1];
        int2 cv2 = csr[e + 2];
        int2 cv3 = csr[e + 3];
        unsigned u0 = y16u[(size_t)cv0.x * 64 + lane];
        unsigned u1 = y16u[(size_t)cv1.x * 64 + lane];
        unsigned u2 = y16u[(size_t)cv2.x * 64 + lane];
        unsigned u3 = y16u[(size_t)cv3.x * 64 + lane];
        float v0 = __int_as_float(cv0.y);
        float v1 = __int_as_float(cv1.y);
        float v2 = __int_as_float(cv2.y);
        float v3 = __int_as_float(cv3.y);
        acc.x += v0 * __uint_as_float(u0 << 16);
        acc.y += v0 * __uint_as_float(u0 & 0xFFFF0000u);
        acc.x += v1 * __uint_as_float(u1 << 16);
        acc.y += v1 * __uint_as_float(u1 & 0xFFFF0000u);
        acc.x += v2 * __uint_as_float(u2 << 16);
        acc.y += v2 * __uint_as_float(u2 & 0xFFFF0000u);
        acc.x += v3 * __uint_as_float(u3 << 16);
        acc.y += v3 * __uint_as_float(u3 & 0xFFFF0000u);
    }
    for (; e < end; ++e) {
        int2 cv = csr[e];
        unsigned u = y16u[(size_t)cv.x * 64 + lane];
        float v = __int_as_float(cv.y);
        acc.x += v * __uint_as_float(u << 16);
        acc.y += v * __uint_as_float(u & 0xFFFF0000u);
    }
    ((float2*)(out + (size_t)node * F))[lane] = acc;
}

// ---------------------------------------------------------------------------
// Fallback (ws too small): bias-init + bf16-y atomic scatter
// ---------------------------------------------------------------------------
__global__ void init_out_kernel(float* __restrict__ out, const float* __restrict__ b) {
    int idx = blockIdx.x * blockDim.x + threadIdx.x;
    const int total4 = N_NODES * F / 4;
    if (idx < total4) {
        int o4 = idx & (F / 4 - 1);
        ((float4*)out)[idx] = ((const float4*)b)[o4];
    }
}

__global__ void __launch_bounds__(256)
scatter_edges_bf16_kernel(const int* __restrict__ rows, const int* __restrict__ cols,
                          const float* __restrict__ vals,
                          const unsigned* __restrict__ y16u, float* __restrict__ out) {
    long long t = (long long)blockIdx.x * blockDim.x + threadIdx.x;
    int e = (int)(t >> 6);
    int lane = (int)(t & 63);
    if (e >= N_EDGES) return;
    int r = rows[e];
    int c = cols[e];
    float v = vals[e];
    unsigned u = y16u[(size_t)c * 64 + lane];
    float* o = out + (size_t)r * F + lane * 2;
    __hip_atomic_fetch_add(o + 0, v * __uint_as_float(u << 16), __ATOMIC_RELAXED, __HIP_MEMORY_SCOPE_AGENT);
    __hip_atomic_fetch_add(o + 1, v * __uint_as_float(u & 0xFFFF0000u), __ATOMIC_RELAXED, __HIP_MEMORY_SCOPE_AGENT);
}

// ---------------------------------------------------------------------------
extern "C" void kernel_launch(void* const* d_in, const int* in_sizes, int n_in,
                              void* d_out, int out_size, void* d_ws, size_t ws_size,
                              hipStream_t stream) {
    const int*   L_rows = (const int*)d_in[0];
    const int*   L_cols = (const int*)d_in[1];
    const float* L_vals = (const float*)d_in[2];
    const float* x      = (const float*)d_in[3];
    const float* W      = (const float*)d_in[4];
    const float* b      = (const float*)d_in[5];
    float* out = (float*)d_out;

    // Workspace layout (bytes):
    //   y16      @ 0          : N*F*2      = 25,600,000
    //   counts_p @ 25,600,000 : N*16*4     =  6,400,000   (1 row per 64B line)
    //   cursor_p @ 32,000,000 : N*16*4     =  6,400,000
    //   row_ptr  @ 38,400,000 : (N+1)*4 -> 400,016
    //   sums     @ 38,800,016 : 400 ints -> 1,600
    //   bases    @ 38,801,616 : 400 ints -> 1,600
    //   csr      @ 38,803,216 : E*8        = 25,600,000
    const size_t OFF_COUNTS = 25600000;
    const size_t OFF_CURSOR = 32000000;
    const size_t OFF_ROWPTR = 38400000;
    const size_t OFF_SUMS   = 38800016;
    const size_t OFF_BASES  = 38801616;
    const size_t OFF_CSR    = 38803216;
    const size_t WS_NEEDED  = 64403216;

    char* ws = (char*)d_ws;
    unsigned short* y16 = (unsigned short*)ws;

    if (ws_size >= WS_NEEDED) {
        int*  counts_p = (int*)(ws + OFF_COUNTS);
        int*  cursor_p = (int*)(ws + OFF_CURSOR);
        int*  row_ptr  = (int*)(ws + OFF_ROWPTR);
        int*  sums     = (int*)(ws + OFF_SUMS);
        int*  bases    = (int*)(ws + OFF_BASES);
        int2* csr      = (int2*)(ws + OFF_CSR);

        hipLaunchKernelGGL(zero_counts_kernel, dim3((400000 + 255) / 256), dim3(256), 0,
                           stream, (int4*)counts_p);
        hipLaunchKernelGGL(hist_kernel, dim3((N_EDGES + 255) / 256), dim3(256), 0, stream,
                           L_rows, counts_p);
        hipLaunchKernelGGL(scanA_kernel, dim3(NB_SCAN), dim3(256), 0, stream,
                           counts_p, sums);
        hipLaunchKernelGGL(scanB_kernel, dim3(1), dim3(512), 0, stream,
                           sums, bases, row_ptr);
        hipLaunchKernelGGL(scanC_kernel, dim3(NB_SCAN), dim3(256), 0, stream,
                           counts_p, bases, row_ptr, cursor_p);
        hipLaunchKernelGGL(fat_gemm_scatter_kernel, dim3(GEMM_BLOCKS + SCAT_BLOCKS),
                           dim3(512), 0, stream,
                           x, W, y16, L_rows, L_cols, L_vals, cursor_p, csr);
        hipLaunchKernelGGL(aggregate_kernel, dim3((N_NODES + 3) / 4), dim3(256), 0,
                           stream, row_ptr, csr, (const unsigned*)y16, b, out);
    } else {
        int total4 = N_NODES * F / 4;
        hipLaunchKernelGGL(init_out_kernel, dim3((total4 + 255) / 256), dim3(256), 0,
                           stream, out, b);
        // gemm-only: grid stops before scatter blocks; cursor/csr unused
        hipLaunchKernelGGL(fat_gemm_scatter_kernel, dim3(GEMM_BLOCKS), dim3(512), 0,
                           stream, x, W, y16, L_rows, L_cols, L_vals,
                           (int*)nullptr, (int2*)nullptr);
        long long threads = (long long)N_EDGES * 64;
        hipLaunchKernelGGL(scatter_edges_bf16_kernel,
                           dim3((int)((threads + 255) / 256)), dim3(256), 0, stream,
                           L_rows, L_cols, L_vals, (const unsigned*)y16, out);
    }
}